// Round 21
// baseline (342.877 us; speedup 1.0000x reference)
//
#include <hip/hip_runtime.h>
#include <stdint.h>

#define SEQ      1024
#define NT       128
#define NBATCH   256
#define MID      512
#define WS_STRIDE 132       // 128 floats + kSum

// In-loop barrier: drain ONLY LDS (state-write visibility); leave the global
// E/M prefetch loads in flight (compiler inserts counted vmcnt at first use).
// __syncthreads() would add vmcnt(0) and expose ~HBM latency every step.
#define BARRIER() asm volatile("s_waitcnt lgkmcnt(0)\n\ts_barrier" ::: "memory")

// emulated bf16-pair dot (R13-proven): 6 ops/pair
#define DOT2ACC(a, su, wu) { \
    a = fmaf(__uint_as_float((wu) << 16),         __uint_as_float((su) << 16),         a); \
    a = fmaf(__uint_as_float((wu) & 0xffff0000u), __uint_as_float((su) & 0xffff0000u), a); }

// 16 NAMED u32 weight regs (bf16 pairs) = 16 VGPRs -> total live ~28 (R13-proven
// resident; every larger demand spilled).
#define RALL(X) X(0) X(1) X(2) X(3) X(4) X(5) X(6) X(7) \
                X(8) X(9) X(10) X(11) X(12) X(13) X(14) X(15)
#define DECLW(k) uint32_t W##k;
#define INITW(k) { \
    float f0_ = __expf(wbase[(2 * (k)    ) * wstr]); \
    float f1_ = __expf(wbase[(2 * (k) + 1) * wstr]); \
    asm("v_cvt_pk_bf16_f32 %0, %1, %2" : "=v"(W##k) : "v"(f0_), "v"(f1_)); }
#define PINW(k)  asm volatile("" : "+v"(W##k));

#define MQ(c, k0, k1, k2, k3) { \
    uint4 u_ = *(const uint4*)(gp + 4 * (c)); \
    DOT2ACC(a0, u_.x, W##k0); \
    DOT2ACC(a1, u_.y, W##k1); \
    DOT2ACC(a2, u_.z, W##k2); \
    DOT2ACC(a3, u_.w, W##k3); }

// 32-tag quarter dot (16 dot2) + cross-q combine (partners = adjacent lanes)
#define MATVEC32(S_) { \
    float a0 = 0.f, a1 = 0.f, a2 = 0.f, a3 = 0.f; \
    MQ(0,0,1,2,3) MQ(1,4,5,6,7) MQ(2,8,9,10,11) MQ(3,12,13,14,15) \
    S_ = (a0 + a1) + (a2 + a3); \
    S_ += __shfl_xor(S_, 1, 64); \
    S_ += __shfl_xor(S_, 2, 64); }

#define BF16_STORE(buf_, val_) { \
    uint32_t pk_; \
    asm("v_cvt_pk_bf16_f32 %0, %1, %2" : "=v"(pk_) : "v"(val_), "v"(val_)); \
    ((unsigned short*)(buf_))[jt] = (unsigned short)(pk_ & 0xffffu); }

// blocks [0,256):    forward chains (batch = blk, steps 1..512)
// blocks [256,512):  backward chains (batch = blk-256, steps 1023..513)
// blocks [512,544):  score gathers (8 batches each)
__global__ __launch_bounds__(512) void crf_chains(
    const float* __restrict__ emissions,   // [B, SEQ, NT]
    const float* __restrict__ transitions, // [NT, NT]
    const int*   __restrict__ tags,        // [B, SEQ]
    const float* __restrict__ mask,        // [B, SEQ]
    float* __restrict__ out,               // [1]
    float* __restrict__ ws)                // [2*256*132]
{
    const int blk = blockIdx.x;
    const int tid = threadIdx.x;

    if (blk >= 2 * NBATCH) {
        // ---------------- score blocks ----------------
        int b    = (blk - 2 * NBATCH) * 8 + (tid >> 6);
        int lane = tid & 63;
        const float* emb = emissions + (size_t)b * SEQ * NT;
        const int*   tgb = tags + (size_t)b * SEQ;
        const float* mkb = mask + (size_t)b * SEQ;
        float sc = 0.f;
        for (int t = lane; t < SEQ; t += 64) {
            int   tg = tgb[t];
            float mt = mkb[t];
            sc += emb[t * NT + tg] * mt;
            if (t >= 1) sc += transitions[tgb[t - 1] * NT + tg] * mt;
        }
#pragma unroll
        for (int o = 32; o > 0; o >>= 1) sc += __shfl_down(sc, o, 64);
        if (lane == 0) atomicAdd(out, -sc * (1.0f / NBATCH));
        return;
    }

    // ---------------- chain block ----------------
    // state = 64 u32 bf16 pairs (tags 2i, 2i+1), double-buffered
    __shared__ __align__(16) uint32_t buf[2][NT / 2];

    const int jt = tid >> 2;   // owned output tag 0..127
    const int q  = tid & 3;    // predecessor quarter (32 tags)

    const bool fwd = (blk < NBATCH);
    const int  b   = fwd ? blk : blk - NBATCH;

    const float* emb = emissions + (size_t)b * SEQ * NT;
    const float* mkb = mask + (size_t)b * SEQ;

    // fwd: expT[32q+2k][jt] (col jt, stride NT); bwd: expT[jt][32q+2k] (row, contig)
    const float* wbase = fwd ? (transitions + (size_t)(32 * q) * NT + jt)
                             : (transitions + (size_t)jt * NT + 32 * q);
    const int    wstr  = fwd ? NT : 1;

    RALL(DECLW)
    RALL(INITW)
    RALL(PINW)

    int   kSum = 0, p = 0;
    float gcur = 0.f, beta = 1.0f;
    float E0, E1, M0, M1;

    if (fwd) {
        gcur = __expf(emb[jt]);
        if (q == 0) BF16_STORE(buf[0], gcur);
        E0 = emb[1 * NT + jt];  E1 = emb[2 * NT + jt];
        M0 = mkb[1];            M1 = mkb[2];
    } else {
        float w0 = __expf(emb[(size_t)(SEQ - 1) * NT + jt]);   // w_1023 (beta=1)
        if (q == 0) BF16_STORE(buf[0], w0);
        E0 = emb[(size_t)(SEQ - 2) * NT + jt];
        E1 = emb[(size_t)(SEQ - 3) * NT + jt];
        M0 = mkb[SEQ - 1];      M1 = mkb[SEQ - 2];
    }
    __syncthreads();

    if (fwd) {
        // ---------- forward: 512 steps, t = 1+s ----------
        for (int s = 0; s < MID; ++s) {
            float En = emb[(size_t)(3 + s) * NT + jt];   // <= 514
            float Mn = mkb[3 + s];
            if (M0 != 0.0f) {
                const uint32_t* gp = buf[p] + 16 * q;
                uint32_t anchor = buf[p][0];
                float sres;
                MATVEC32(sres);
                int   e  = (int)((anchor >> 7) & 0xff);  // bf16 exp of tag0
                float rc = __uint_as_float((uint32_t)(254 - e) << 23);
                kSum += e - 127;
                if (q == 0) {
                    gcur = sres * rc * __expf(E0);
                    BF16_STORE(buf[p ^ 1], gcur);
                }
                p ^= 1;
            }
            BARRIER();
            E0 = E1; E1 = En; M0 = M1; M1 = Mn;
        }
        float* wsb = ws + (size_t)b * WS_STRIDE;
        if (q == 0)  wsb[jt] = gcur;          // alpha_512 (pow2-scaled)
        if (tid == 0) wsb[128] = (float)kSum;
    } else {
        // ---------- backward: 511 steps, t = 1023-s; buf holds w = beta.*expE ----------
        for (int s = 0; s < MID - 1; ++s) {
            float En = emb[(size_t)(SEQ - 4 - s) * NT + jt];  // >= 510
            float Mn = mkb[SEQ - 3 - s];
            {
                const uint32_t* gp = buf[p] + 16 * q;
                uint32_t anchor = buf[p][0];
                float sres;
                MATVEC32(sres);
                int   e  = (int)((anchor >> 7) & 0xff);
                float rc = __uint_as_float((uint32_t)(254 - e) << 23);
                kSum += e - 127;
                float bn = (M0 != 0.0f) ? sres * rc : beta * rc;
                beta = bn;
                if (q == 0) {
                    float g = bn * __expf(E0);   // w_{t-1}
                    BF16_STORE(buf[p ^ 1], g);
                }
                p ^= 1;
            }
            BARRIER();
            E0 = E1; E1 = En; M0 = M1; M1 = Mn;
        }
        float* wsb = ws + (size_t)(NBATCH + b) * WS_STRIDE;
        if (q == 0)  wsb[jt] = beta;          // beta_512 (pow2-scaled)
        if (tid == 0) wsb[128] = (float)kSum;
    }
}

// Z = sum_i alpha_MID[i] * beta_MID[i] * 2^(kF+kB)
__global__ __launch_bounds__(64) void crf_combine(
    const float* __restrict__ ws, float* __restrict__ out)
{
    int b    = blockIdx.x;
    int lane = threadIdx.x;
    const float* af = ws + (size_t)b * WS_STRIDE;
    const float* bf = ws + (size_t)(NBATCH + b) * WS_STRIDE;
    float d = af[lane] * bf[lane] + af[lane + 64] * bf[lane + 64];
#pragma unroll
    for (int o = 32; o > 0; o >>= 1) d += __shfl_down(d, o, 64);
    if (lane == 0) {
        float logZ = __logf(d) + (af[128] + bf[128]) * 0.69314718055994531f;
        atomicAdd(out, logZ * (1.0f / NBATCH));
    }
}

extern "C" void kernel_launch(void* const* d_in, const int* in_sizes, int n_in,
                              void* d_out, int out_size, void* d_ws, size_t ws_size,
                              hipStream_t stream) {
    const float* emissions   = (const float*)d_in[0];
    const float* transitions = (const float*)d_in[1];
    const int*   tags        = (const int*)d_in[2];
    const float* mask        = (const float*)d_in[3];
    float*       out         = (float*)d_out;
    float*       ws          = (float*)d_ws;

    hipMemsetAsync(out, 0, sizeof(float), stream);
    crf_chains<<<2 * NBATCH + 32, 512, 0, stream>>>(
        emissions, transitions, tags, mask, out, ws);
    crf_combine<<<NBATCH, 64, 0, stream>>>(ws, out);
}